// Round 20
// baseline (385.431 us; speedup 1.0000x reference)
//
#include <hip/hip_runtime.h>
#include <hip/hip_bf16.h>
#include <math.h>

#define DD 2048
#define SS 8192
#define VV 32002
#define RR 7
#define GATE 6144

typedef unsigned short u16;
typedef __attribute__((ext_vector_type(8))) unsigned short u16x8;
typedef __attribute__((ext_vector_type(8))) short bfrag;   // 8 bf16 = 4 VGPRs
typedef __attribute__((ext_vector_type(4))) float f32x4;

// ---- static device scratch: referenced ONLY from device code ----
__device__ __attribute__((aligned(256))) u16 g_ah[(size_t)SS * DD];   // enc as bf16 (32 MB)
__device__ __attribute__((aligned(256))) u16 g_bh[(size_t)DD * DD];   // W_enc as bf16 (8 MB)
__device__ __attribute__((aligned(256))) float g_gia[GATE], g_gha[GATE], g_gib[GATE], g_ghb[GATE];
__device__ __attribute__((aligned(256))) float g_co[DD], g_cc[DD], g_ctx[DD], g_cb[DD];
__device__ __attribute__((aligned(256))) float g_alpha[SS];
__device__ __attribute__((aligned(256))) float g_scores[SS];
__device__ __attribute__((aligned(256))) float g_scores2[SS];   // dummy target for timing dispatch

__device__ __forceinline__ float fsigmoid(float x) { return 1.0f / (1.0f + __expf(-x)); }
__device__ __forceinline__ float ftanh(float x)    { return 1.0f - 2.0f / (__expf(2.0f * x) + 1.0f); }
__device__ __forceinline__ u16 f2bf(float v) {
    union { float f; unsigned int i; } c; c.f = v;
    return (u16)((c.i + 0x7FFF + ((c.i >> 16) & 1)) >> 16);   // RNE
}
__device__ __forceinline__ float bf2f(u16 u) {
    union { unsigned int i; float f; } c; c.i = ((unsigned int)u) << 16; return c.f;
}
__device__ __forceinline__ void gload16(const void* g, void* l) {
    __builtin_amdgcn_global_load_lds(
        (const __attribute__((address_space(1))) void*)g,
        (__attribute__((address_space(3))) void*)l, 16, 0, 0);
}

__global__ void diag_k(float* out, float v) { out[0] = v; }

// ---------------- fused presplit: blocks [0,8192) -> enc, [8192,10240) -> W_enc; + zero-init ----------------
__global__ __launch_bounds__(256) void presplit_all_k(const float* __restrict__ enc,
                                                      const float* __restrict__ wenc) {
    int b = blockIdx.x;
    const float* src;
    u16* dst;
    size_t i;
    if (b < SS) { src = enc;  dst = g_ah; i = ((size_t)b * 256 + threadIdx.x) * 8; }
    else        { src = wenc; dst = g_bh; i = ((size_t)(b - SS) * 256 + threadIdx.x) * 8; }
    f32x4 v0 = *(const f32x4*)&src[i];
    f32x4 v1 = *(const f32x4*)&src[i + 4];
    u16x8 h;
#pragma unroll
    for (int e = 0; e < 4; ++e) { h[e] = f2bf(v0[e]); h[4 + e] = f2bf(v1[e]); }
    *(u16x8*)&dst[i] = h;
    if (b >= SS) {   // zero accumulators (2048 blocks x 256 threads covers SS)
        int gt = (b - SS) * 256 + threadIdx.x;
        if (gt < SS) g_scores[gt] = 0.0f;
        if (gt < DD) g_ctx[gt] = 0.0f;
    }
}

// ---------------- fused matvec pair: PAIR 0 -> {gi_a, gh_a}, PAIR 1 -> {gi_b, gh_b} ----------------
template<int PAIR>
__global__ __launch_bounds__(256) void matvec2_k(const float* __restrict__ W0,
                                                 const float* __restrict__ W1,
                                                 const float* __restrict__ x0_in,
                                                 const float* __restrict__ x1_in,
                                                 const float* __restrict__ b0,
                                                 const float* __restrict__ b1) {
    const int half = blockIdx.x >= (GATE / 4);
    const float* W    = half ? W1 : W0;
    const float* bias = half ? b1 : b0;
    const float* x;
    float* out;
    if (PAIR == 0) { x = half ? x1_in : x0_in; out = half ? g_gha : g_gia; }
    else           { x = half ? g_co  : g_ctx; out = half ? g_ghb : g_gib; }
    int wv = threadIdx.x >> 6, lane = threadIdx.x & 63;
    int row = (blockIdx.x - half * (GATE / 4)) * 4 + wv;
    const float* wp = W + (size_t)row * DD;
    float acc = 0.0f;
#pragma unroll
    for (int j = 0; j < 4; ++j) {
        int base = j * 512 + lane * 8;
        f32x4 w0 = *(const f32x4*)&wp[base];
        f32x4 w1 = *(const f32x4*)&wp[base + 4];
        f32x4 x0 = *(const f32x4*)&x[base];
        f32x4 x1 = *(const f32x4*)&x[base + 4];
#pragma unroll
        for (int e = 0; e < 4; ++e) acc += w0[e] * x0[e] + w1[e] * x1[e];
    }
#pragma unroll
    for (int o = 1; o < 64; o <<= 1) acc += __shfl_xor(acc, o);
    if (lane == 0) out[row] = acc + bias[row];
}

// ---------------- GRU pointwise ----------------
template<int B>
__global__ void gru_out_k(const float* __restrict__ h_in, float* __restrict__ out_f) {
    const float* gi = B ? g_gib : g_gia;
    const float* gh = B ? g_ghb : g_gha;
    int d = blockIdx.x * 256 + threadIdx.x;
    float hh = B ? g_co[d] : h_in[d];
    float r = fsigmoid(gi[d] + gh[d]);
    float z = fsigmoid(gi[DD + d] + gh[DD + d]);
    float n = ftanh(gi[2 * DD + d] + r * gh[2 * DD + d]);
    float c = (1.0f - z) * n + z * hh;
    if (B) { g_cb[d] = c; out_f[d] = c; }
    else   { g_co[d] = c; }
}

// ---------------- cc[n] = W_co[n].c_o + W_cov[n].cov + b_enc+b_co+b_cov ----------------
__global__ __launch_bounds__(256) void cc_k(const float* __restrict__ Wco, const float* __restrict__ Wcov,
                                            const float* __restrict__ cov,
                                            const float* __restrict__ benc, const float* __restrict__ bco,
                                            const float* __restrict__ bcov) {
    int wv = threadIdx.x >> 6, lane = threadIdx.x & 63;
    int row = blockIdx.x * 4 + wv;
    const float* p1 = Wco + (size_t)row * DD;
    const float* p2 = Wcov + (size_t)row * DD;
    float acc = 0.0f;
#pragma unroll
    for (int j = 0; j < 4; ++j) {
        int base = j * 512 + lane * 8;
        f32x4 u0 = *(const f32x4*)&p1[base];
        f32x4 u1 = *(const f32x4*)&p1[base + 4];
        f32x4 v0 = *(const f32x4*)&p2[base];
        f32x4 v1 = *(const f32x4*)&p2[base + 4];
        f32x4 a0 = *(const f32x4*)&g_co[base];
        f32x4 a1 = *(const f32x4*)&g_co[base + 4];
        f32x4 b0 = *(const f32x4*)&cov[base];
        f32x4 b1 = *(const f32x4*)&cov[base + 4];
#pragma unroll
        for (int e = 0; e < 4; ++e)
            acc += u0[e] * a0[e] + u1[e] * a1[e] + v0[e] * b0[e] + v1[e] * b1[e];
    }
#pragma unroll
    for (int o = 1; o < 64; o <<= 1) acc += __shfl_xor(acc, o);
    if (lane == 0) g_cc[row] = acc + benc[row] + bco[row] + bcov[row];
}

// ---------------- fused e-GEMM + tanh-score epilogue (round-18 config) ----------------
// DUMMY=1 -> identical work into g_scores2 (self-timing dispatch; never read).
template<int DUMMY>
__global__ __launch_bounds__(256) void score_gemm_k(const float* __restrict__ Wsc) {
    float* target = DUMMY ? g_scores2 : g_scores;
    __shared__ u16 As[2][128 * 32];
    __shared__ u16 Bs[2][128 * 32];
    const int bid = blockIdx.x;
    const int swz = (bid & 7) * 128 + (bid >> 3);   // XCD-aware (1024 % 8 == 0)
    const int bm = swz >> 4;      // 0..63
    const int bn = swz & 15;      // 0..15
    const int tid = threadIdx.x;
    const int wave = tid >> 6, lane = tid & 63;
    const int wr = wave >> 1, wc = wave & 1;
    const int srow = lane >> 2;
    const int scol = (((lane & 3) ^ ((lane >> 4) & 3)) * 8);   // pre-swizzled source col
    const int rsel = lane & 15;
    const int kq = (((lane >> 4) ^ ((lane >> 2) & 3)) * 8);    // swizzled read col
    const int c0 = wave * 2, c1 = wave * 2 + 1;

    f32x4 acc[4][4];
#pragma unroll
    for (int m = 0; m < 4; ++m)
#pragma unroll
        for (int n = 0; n < 4; ++n) acc[m][n] = f32x4{0.f, 0.f, 0.f, 0.f};

    const u16* gA = g_ah + (size_t)(bm * 128) * DD;
    const u16* gB = g_bh + (size_t)(bn * 128) * DD;
    const size_t off0 = (size_t)(c0 * 16 + srow) * DD + scol;
    const size_t off1 = (size_t)(c1 * 16 + srow) * DD + scol;

    gload16(gA + off0, &As[0][c0 * 512]);
    gload16(gA + off1, &As[0][c1 * 512]);
    gload16(gB + off0, &Bs[0][c0 * 512]);
    gload16(gB + off1, &Bs[0][c1 * 512]);
    __syncthreads();

    int cur = 0;
    for (int step = 0; step < 64; ++step) {
        if (step < 63) {
            size_t k1 = (size_t)(step + 1) * 32;
            gload16(gA + off0 + k1, &As[cur ^ 1][c0 * 512]);
            gload16(gA + off1 + k1, &As[cur ^ 1][c1 * 512]);
            gload16(gB + off0 + k1, &Bs[cur ^ 1][c0 * 512]);
            gload16(gB + off1 + k1, &Bs[cur ^ 1][c1 * 512]);
        }
        bfrag a[4], b[4];
#pragma unroll
        for (int m = 0; m < 4; ++m) a[m] = *(const bfrag*)&As[cur][(wr * 64 + m * 16 + rsel) * 32 + kq];
#pragma unroll
        for (int n = 0; n < 4; ++n) b[n] = *(const bfrag*)&Bs[cur][(wc * 64 + n * 16 + rsel) * 32 + kq];
#pragma unroll
        for (int m = 0; m < 4; ++m)
#pragma unroll
            for (int n = 0; n < 4; ++n)
                acc[m][n] = __builtin_amdgcn_mfma_f32_16x16x32_bf16(a[m], b[n], acc[m][n], 0, 0, 0);
        __syncthreads();
        cur ^= 1;
    }

    const int cl = lane & 15, gq = lane >> 4;
    float ccv[4], wv[4];
#pragma unroll
    for (int nf = 0; nf < 4; ++nf) {
        int n = bn * 128 + wc * 64 + nf * 16 + cl;
        ccv[nf] = g_cc[n];
        wv[nf] = Wsc[n];
    }
#pragma unroll
    for (int m = 0; m < 4; ++m) {
#pragma unroll
        for (int r = 0; r < 4; ++r) {
            float v = 0.0f;
#pragma unroll
            for (int nf = 0; nf < 4; ++nf) v += ftanh(acc[m][nf][r] + ccv[nf]) * wv[nf];
            v += __shfl_xor(v, 1); v += __shfl_xor(v, 2);
            v += __shfl_xor(v, 4); v += __shfl_xor(v, 8);
            if (cl == 0) atomicAdd(&target[bm * 128 + wr * 64 + m * 16 + gq * 4 + r], v);
        }
    }
}

// ---------------- softmax over 8192 scores ----------------
__global__ __launch_bounds__(1024) void softmax_k(float* __restrict__ out_alpha) {
    __shared__ float red[16];
    __shared__ float sval;
    int t = threadIdx.x, lane = t & 63, w = t >> 6;
    float loc[8];
    float m = -1e30f;
#pragma unroll
    for (int i = 0; i < 8; ++i) {
        loc[i] = g_scores[t + i * 1024];
        m = fmaxf(m, loc[i]);
    }
#pragma unroll
    for (int o = 1; o < 64; o <<= 1) m = fmaxf(m, __shfl_xor(m, o));
    if (lane == 0) red[w] = m;
    __syncthreads();
    if (t == 0) { float mm = red[0]; for (int i = 1; i < 16; ++i) mm = fmaxf(mm, red[i]); sval = mm; }
    __syncthreads();
    float mx = sval, s = 0.0f;
#pragma unroll
    for (int i = 0; i < 8; ++i) { loc[i] = __expf(loc[i] - mx); s += loc[i]; }
#pragma unroll
    for (int o = 1; o < 64; o <<= 1) s += __shfl_xor(s, o);
    if (lane == 0) red[w] = s;
    __syncthreads();
    if (t == 0) { float ss = 0; for (int i = 0; i < 16; ++i) ss += red[i]; sval = ss; }
    __syncthreads();
    float inv = 1.0f / sval;
#pragma unroll
    for (int i = 0; i < 8; ++i) {
        float a = loc[i] * inv;
        g_alpha[t + i * 1024] = a;
        out_alpha[t + i * 1024] = a;
    }
}

// ---------------- ctx += alpha @ enc  (bf16 enc from g_ah) ----------------
__global__ __launch_bounds__(256) void ctx_partial_k() {
    int t = threadIdx.x, b = blockIdx.x;   // 128 blocks x 64 s-rows
    int d0 = t * 8;
    float acc[8] = {0, 0, 0, 0, 0, 0, 0, 0};
    int s0 = b * 64;
    for (int s = s0; s < s0 + 64; ++s) {
        u16x8 v = *(const u16x8*)&g_ah[(size_t)s * DD + d0];
        float a = g_alpha[s];
#pragma unroll
        for (int e = 0; e < 8; ++e) acc[e] += a * bf2f(v[e]);
    }
#pragma unroll
    for (int e = 0; e < 8; ++e) atomicAdd(&g_ctx[d0 + e], acc[e]);
}

// ---------------- heads ----------------
__global__ __launch_bounds__(256) void heads_k(const float* __restrict__ Wsym, const float* __restrict__ bsym,
                                               const float* __restrict__ Wrel, const float* __restrict__ brel,
                                               float* __restrict__ out) {
    int wv = threadIdx.x >> 6, lane = threadIdx.x & 63;
    int row = blockIdx.x * 4 + wv;
    if (row >= VV + RR) return;
    const float* wp;
    float bb;
    if (row < VV) { wp = Wsym + (size_t)row * DD; bb = bsym[row]; }
    else          { wp = Wrel + (size_t)(row - VV) * DD; bb = brel[row - VV]; }
    float acc = 0.0f;
#pragma unroll
    for (int j = 0; j < 4; ++j) {
        int base = j * 512 + lane * 8;
        f32x4 w0 = *(const f32x4*)&wp[base];
        f32x4 w1 = *(const f32x4*)&wp[base + 4];
        f32x4 x0 = *(const f32x4*)&g_cb[base];
        f32x4 x1 = *(const f32x4*)&g_cb[base + 4];
#pragma unroll
        for (int e = 0; e < 4; ++e) acc += w0[e] * x0[e] + w1[e] * x1[e];
    }
#pragma unroll
    for (int o = 1; o < 64; o <<= 1) acc += __shfl_xor(acc, o);
    if (lane == 0) out[row] = acc + bb;
}

extern "C" void kernel_launch(void* const* d_in, const int* in_sizes, int n_in,
                              void* d_out, int out_size, void* d_ws, size_t ws_size,
                              hipStream_t stream) {
    float* out = (float*)d_out;   // f32 outputs

    static const int expected[24] = {
        SS * DD, DD, DD, DD,
        3 * DD * DD, 3 * DD * DD, 3 * DD, 3 * DD,
        3 * DD * DD, 3 * DD * DD, 3 * DD, 3 * DD,
        DD * DD, DD, DD * DD, DD, DD * DD, DD,
        DD, 1, VV * DD, VV, RR * DD, RR
    };
    if (n_in != 24) { diag_k<<<1, 1, 0, stream>>>(out, 4.0e7f); return; }
    for (int i = 0; i < 24; ++i)
        if (in_sizes[i] != expected[i]) { diag_k<<<1, 1, 0, stream>>>(out, 3.0e7f + (i + 1) * 1.0e5f); return; }

    const float* enc     = (const float*)d_in[0];
    const float* cprev   = (const float*)d_in[1];
    const float* partner = (const float*)d_in[2];
    const float* cov     = (const float*)d_in[3];
    const float* Wih_a   = (const float*)d_in[4];
    const float* Whh_a   = (const float*)d_in[5];
    const float* bih_a   = (const float*)d_in[6];
    const float* bhh_a   = (const float*)d_in[7];
    const float* Wih_b   = (const float*)d_in[8];
    const float* Whh_b   = (const float*)d_in[9];
    const float* bih_b   = (const float*)d_in[10];
    const float* bhh_b   = (const float*)d_in[11];
    const float* W_enc   = (const float*)d_in[12];
    const float* b_enc   = (const float*)d_in[13];
    const float* W_co    = (const float*)d_in[14];
    const float* b_co    = (const float*)d_in[15];
    const float* W_cov   = (const float*)d_in[16];
    const float* b_cov   = (const float*)d_in[17];
    const float* W_score = (const float*)d_in[18];
    const float* W_sym   = (const float*)d_in[20];
    const float* b_sym   = (const float*)d_in[21];
    const float* W_rel   = (const float*)d_in[22];
    const float* b_rel   = (const float*)d_in[23];

    presplit_all_k<<<SS + DD * DD / (256 * 8), 256, 0, stream>>>(enc, W_enc);
    matvec2_k<0><<<2 * (GATE / 4), 256, 0, stream>>>(Wih_a, Whh_a, partner, cprev, bih_a, bhh_a);
    gru_out_k<0><<<8, 256, 0, stream>>>(cprev, nullptr);
    cc_k<<<DD / 4, 256, 0, stream>>>(W_co, W_cov, cov, b_enc, b_co, b_cov);
    score_gemm_k<0><<<1024, 256, 0, stream>>>(W_score);
    score_gemm_k<1><<<1024, 256, 0, stream>>>(W_score);   // TIMING PROBE: dur_us delta = GEMM time
    softmax_k<<<1, 1024, 0, stream>>>(out + VV + RR + DD);
    ctx_partial_k<<<128, 256, 0, stream>>>();
    matvec2_k<1><<<2 * (GATE / 4), 256, 0, stream>>>(Wih_b, Whh_b, nullptr, nullptr, bih_b, bhh_b);
    gru_out_k<1><<<8, 256, 0, stream>>>(cprev, out + VV + RR);
    heads_k<<<(VV + RR + 3) / 4, 256, 0, stream>>>(W_sym, b_sym, W_rel, b_rel, out);
}

// Round 21
// 263.669 us; speedup vs baseline: 1.4618x; 1.4618x over previous
//
#include <hip/hip_runtime.h>
#include <hip/hip_bf16.h>
#include <math.h>

#define DD 2048
#define SS 8192
#define VV 32002
#define RR 7
#define GATE 6144

typedef unsigned short u16;
typedef __attribute__((ext_vector_type(8))) unsigned short u16x8;
typedef __attribute__((ext_vector_type(8))) short bfrag;   // 8 bf16 = 4 VGPRs
typedef __attribute__((ext_vector_type(4))) float f32x4;

// ---- static device scratch: referenced ONLY from device code ----
__device__ __attribute__((aligned(256))) u16 g_ah[(size_t)SS * DD];   // enc as bf16 (32 MB)
__device__ __attribute__((aligned(256))) u16 g_bh[(size_t)DD * DD];   // W_enc as bf16 (8 MB)
__device__ __attribute__((aligned(256))) float g_gia[GATE], g_gha[GATE], g_gib[GATE], g_ghb[GATE];
__device__ __attribute__((aligned(256))) float g_co[DD], g_cc[DD], g_ctx[DD], g_cb[DD];
__device__ __attribute__((aligned(256))) float g_alpha[SS];
__device__ __attribute__((aligned(256))) float g_scores[SS];

__device__ __forceinline__ float fsigmoid(float x) { return 1.0f / (1.0f + __expf(-x)); }
__device__ __forceinline__ float ftanh(float x)    { return 1.0f - 2.0f / (__expf(2.0f * x) + 1.0f); }
__device__ __forceinline__ u16 f2bf(float v) {
    union { float f; unsigned int i; } c; c.f = v;
    return (u16)((c.i + 0x7FFF + ((c.i >> 16) & 1)) >> 16);   // RNE
}
__device__ __forceinline__ float bf2f(u16 u) {
    union { unsigned int i; float f; } c; c.i = ((unsigned int)u) << 16; return c.f;
}
__device__ __forceinline__ void gload16(const void* g, void* l) {
    __builtin_amdgcn_global_load_lds(
        (const __attribute__((address_space(1))) void*)g,
        (__attribute__((address_space(3))) void*)l, 16, 0, 0);
}

__global__ void diag_k(float* out, float v) { out[0] = v; }

// ---------------- fused presplit: blocks [0,8192) -> enc, [8192,10240) -> W_enc; + zero-init ----------------
__global__ __launch_bounds__(256) void presplit_all_k(const float* __restrict__ enc,
                                                      const float* __restrict__ wenc) {
    int b = blockIdx.x;
    const float* src;
    u16* dst;
    size_t i;
    if (b < SS) { src = enc;  dst = g_ah; i = ((size_t)b * 256 + threadIdx.x) * 8; }
    else        { src = wenc; dst = g_bh; i = ((size_t)(b - SS) * 256 + threadIdx.x) * 8; }
    f32x4 v0 = *(const f32x4*)&src[i];
    f32x4 v1 = *(const f32x4*)&src[i + 4];
    u16x8 h;
#pragma unroll
    for (int e = 0; e < 4; ++e) { h[e] = f2bf(v0[e]); h[4 + e] = f2bf(v1[e]); }
    *(u16x8*)&dst[i] = h;
    if (b >= SS) {   // zero accumulators (2048 blocks x 256 threads covers SS)
        int gt = (b - SS) * 256 + threadIdx.x;
        if (gt < SS) g_scores[gt] = 0.0f;
        if (gt < DD) g_ctx[gt] = 0.0f;
    }
}

// ---------------- fused matvec pair: PAIR 0 -> {gi_a, gh_a}, PAIR 1 -> {gi_b, gh_b} ----------------
template<int PAIR>
__global__ __launch_bounds__(256) void matvec2_k(const float* __restrict__ W0,
                                                 const float* __restrict__ W1,
                                                 const float* __restrict__ x0_in,
                                                 const float* __restrict__ x1_in,
                                                 const float* __restrict__ b0,
                                                 const float* __restrict__ b1) {
    const int half = blockIdx.x >= (GATE / 4);
    const float* W    = half ? W1 : W0;
    const float* bias = half ? b1 : b0;
    const float* x;
    float* out;
    if (PAIR == 0) { x = half ? x1_in : x0_in; out = half ? g_gha : g_gia; }
    else           { x = half ? g_co  : g_ctx; out = half ? g_ghb : g_gib; }
    int wv = threadIdx.x >> 6, lane = threadIdx.x & 63;
    int row = (blockIdx.x - half * (GATE / 4)) * 4 + wv;
    const float* wp = W + (size_t)row * DD;
    float acc = 0.0f;
#pragma unroll
    for (int j = 0; j < 4; ++j) {
        int base = j * 512 + lane * 8;
        f32x4 w0 = *(const f32x4*)&wp[base];
        f32x4 w1 = *(const f32x4*)&wp[base + 4];
        f32x4 x0 = *(const f32x4*)&x[base];
        f32x4 x1 = *(const f32x4*)&x[base + 4];
#pragma unroll
        for (int e = 0; e < 4; ++e) acc += w0[e] * x0[e] + w1[e] * x1[e];
    }
#pragma unroll
    for (int o = 1; o < 64; o <<= 1) acc += __shfl_xor(acc, o);
    if (lane == 0) out[row] = acc + bias[row];
}

// ---------------- GRU pointwise ----------------
template<int B>
__global__ void gru_out_k(const float* __restrict__ h_in, float* __restrict__ out_f) {
    const float* gi = B ? g_gib : g_gia;
    const float* gh = B ? g_ghb : g_gha;
    int d = blockIdx.x * 256 + threadIdx.x;
    float hh = B ? g_co[d] : h_in[d];
    float r = fsigmoid(gi[d] + gh[d]);
    float z = fsigmoid(gi[DD + d] + gh[DD + d]);
    float n = ftanh(gi[2 * DD + d] + r * gh[2 * DD + d]);
    float c = (1.0f - z) * n + z * hh;
    if (B) { g_cb[d] = c; out_f[d] = c; }
    else   { g_co[d] = c; }
}

// ---------------- cc[n] = W_co[n].c_o + W_cov[n].cov + b_enc+b_co+b_cov ----------------
__global__ __launch_bounds__(256) void cc_k(const float* __restrict__ Wco, const float* __restrict__ Wcov,
                                            const float* __restrict__ cov,
                                            const float* __restrict__ benc, const float* __restrict__ bco,
                                            const float* __restrict__ bcov) {
    int wv = threadIdx.x >> 6, lane = threadIdx.x & 63;
    int row = blockIdx.x * 4 + wv;
    const float* p1 = Wco + (size_t)row * DD;
    const float* p2 = Wcov + (size_t)row * DD;
    float acc = 0.0f;
#pragma unroll
    for (int j = 0; j < 4; ++j) {
        int base = j * 512 + lane * 8;
        f32x4 u0 = *(const f32x4*)&p1[base];
        f32x4 u1 = *(const f32x4*)&p1[base + 4];
        f32x4 v0 = *(const f32x4*)&p2[base];
        f32x4 v1 = *(const f32x4*)&p2[base + 4];
        f32x4 a0 = *(const f32x4*)&g_co[base];
        f32x4 a1 = *(const f32x4*)&g_co[base + 4];
        f32x4 b0 = *(const f32x4*)&cov[base];
        f32x4 b1 = *(const f32x4*)&cov[base + 4];
#pragma unroll
        for (int e = 0; e < 4; ++e)
            acc += u0[e] * a0[e] + u1[e] * a1[e] + v0[e] * b0[e] + v1[e] * b1[e];
    }
#pragma unroll
    for (int o = 1; o < 64; o <<= 1) acc += __shfl_xor(acc, o);
    if (lane == 0) g_cc[row] = acc + benc[row] + bco[row] + bcov[row];
}

// ---------------- fused e-GEMM + tanh-score epilogue ----------------
// T3+T4: dbuf prefetch with COUNTED vmcnt(4) + raw s_barrier — prefetch loads stay
// in flight across the barrier (never drained to 0 in the main loop).
__global__ __launch_bounds__(256) void score_gemm_k(const float* __restrict__ Wsc) {
    __shared__ u16 As[2][128 * 32];
    __shared__ u16 Bs[2][128 * 32];
    const int bid = blockIdx.x;
    const int swz = (bid & 7) * 128 + (bid >> 3);   // XCD-aware (1024 % 8 == 0)
    const int bm = swz >> 4;      // 0..63
    const int bn = swz & 15;      // 0..15
    const int tid = threadIdx.x;
    const int wave = tid >> 6, lane = tid & 63;
    const int wr = wave >> 1, wc = wave & 1;
    const int srow = lane >> 2;
    const int scol = (((lane & 3) ^ ((lane >> 4) & 3)) * 8);   // pre-swizzled source col
    const int rsel = lane & 15;
    const int kq = (((lane >> 4) ^ ((lane >> 2) & 3)) * 8);    // swizzled read col
    const int c0 = wave * 2, c1 = wave * 2 + 1;

    f32x4 acc[4][4];
#pragma unroll
    for (int m = 0; m < 4; ++m)
#pragma unroll
        for (int n = 0; n < 4; ++n) acc[m][n] = f32x4{0.f, 0.f, 0.f, 0.f};

    const u16* gA = g_ah + (size_t)(bm * 128) * DD;
    const u16* gB = g_bh + (size_t)(bn * 128) * DD;
    const size_t off0 = (size_t)(c0 * 16 + srow) * DD + scol;
    const size_t off1 = (size_t)(c1 * 16 + srow) * DD + scol;

    // prologue: stage tile 0 into buffer 0 (4 loads in flight)
    gload16(gA + off0, &As[0][c0 * 512]);
    gload16(gA + off1, &As[0][c1 * 512]);
    gload16(gB + off0, &Bs[0][c0 * 512]);
    gload16(gB + off1, &Bs[0][c1 * 512]);

    int cur = 0;
    for (int step = 0; step < 64; ++step) {
        if (step < 63) {
            // issue next-tile loads (4) — they remain in flight ACROSS the barrier
            size_t k1 = (size_t)(step + 1) * 32;
            gload16(gA + off0 + k1, &As[cur ^ 1][c0 * 512]);
            gload16(gA + off1 + k1, &As[cur ^ 1][c1 * 512]);
            gload16(gB + off0 + k1, &Bs[cur ^ 1][c0 * 512]);
            gload16(gB + off1 + k1, &Bs[cur ^ 1][c1 * 512]);
            asm volatile("s_waitcnt vmcnt(4)" ::: "memory");   // tile-t loads done; t+1 in flight
        } else {
            asm volatile("s_waitcnt vmcnt(0)" ::: "memory");   // epilogue drain
        }
        __builtin_amdgcn_s_barrier();            // all waves: tile-t writes visible
        __builtin_amdgcn_sched_barrier(0);       // keep ds_reads after the barrier
        bfrag a[4], b[4];
#pragma unroll
        for (int m = 0; m < 4; ++m) a[m] = *(const bfrag*)&As[cur][(wr * 64 + m * 16 + rsel) * 32 + kq];
#pragma unroll
        for (int n = 0; n < 4; ++n) b[n] = *(const bfrag*)&Bs[cur][(wc * 64 + n * 16 + rsel) * 32 + kq];
#pragma unroll
        for (int m = 0; m < 4; ++m)
#pragma unroll
            for (int n = 0; n < 4; ++n)
                acc[m][n] = __builtin_amdgcn_mfma_f32_16x16x32_bf16(a[m], b[n], acc[m][n], 0, 0, 0);
        __builtin_amdgcn_s_barrier();            // reads of buf cur done before next-iter overwrite
        __builtin_amdgcn_sched_barrier(0);       // prevent next-iter gload hoist above this point
        cur ^= 1;
    }

    // epilogue: tanh + weighted reduce over this wave's 64 n-columns -> atomic scores
    const int cl = lane & 15, gq = lane >> 4;
    float ccv[4], wv[4];
#pragma unroll
    for (int nf = 0; nf < 4; ++nf) {
        int n = bn * 128 + wc * 64 + nf * 16 + cl;
        ccv[nf] = g_cc[n];
        wv[nf] = Wsc[n];
    }
#pragma unroll
    for (int m = 0; m < 4; ++m) {
#pragma unroll
        for (int r = 0; r < 4; ++r) {
            float v = 0.0f;
#pragma unroll
            for (int nf = 0; nf < 4; ++nf) v += ftanh(acc[m][nf][r] + ccv[nf]) * wv[nf];
            v += __shfl_xor(v, 1); v += __shfl_xor(v, 2);
            v += __shfl_xor(v, 4); v += __shfl_xor(v, 8);
            if (cl == 0) atomicAdd(&g_scores[bm * 128 + wr * 64 + m * 16 + gq * 4 + r], v);
        }
    }
}

// ---------------- softmax over 8192 scores ----------------
__global__ __launch_bounds__(1024) void softmax_k(float* __restrict__ out_alpha) {
    __shared__ float red[16];
    __shared__ float sval;
    int t = threadIdx.x, lane = t & 63, w = t >> 6;
    float loc[8];
    float m = -1e30f;
#pragma unroll
    for (int i = 0; i < 8; ++i) {
        loc[i] = g_scores[t + i * 1024];
        m = fmaxf(m, loc[i]);
    }
#pragma unroll
    for (int o = 1; o < 64; o <<= 1) m = fmaxf(m, __shfl_xor(m, o));
    if (lane == 0) red[w] = m;
    __syncthreads();
    if (t == 0) { float mm = red[0]; for (int i = 1; i < 16; ++i) mm = fmaxf(mm, red[i]); sval = mm; }
    __syncthreads();
    float mx = sval, s = 0.0f;
#pragma unroll
    for (int i = 0; i < 8; ++i) { loc[i] = __expf(loc[i] - mx); s += loc[i]; }
#pragma unroll
    for (int o = 1; o < 64; o <<= 1) s += __shfl_xor(s, o);
    if (lane == 0) red[w] = s;
    __syncthreads();
    if (t == 0) { float ss = 0; for (int i = 0; i < 16; ++i) ss += red[i]; sval = ss; }
    __syncthreads();
    float inv = 1.0f / sval;
#pragma unroll
    for (int i = 0; i < 8; ++i) {
        float a = loc[i] * inv;
        g_alpha[t + i * 1024] = a;
        out_alpha[t + i * 1024] = a;
    }
}

// ---------------- ctx += alpha @ enc  (bf16 enc from g_ah) ----------------
__global__ __launch_bounds__(256) void ctx_partial_k() {
    int t = threadIdx.x, b = blockIdx.x;   // 128 blocks x 64 s-rows
    int d0 = t * 8;
    float acc[8] = {0, 0, 0, 0, 0, 0, 0, 0};
    int s0 = b * 64;
    for (int s = s0; s < s0 + 64; ++s) {
        u16x8 v = *(const u16x8*)&g_ah[(size_t)s * DD + d0];
        float a = g_alpha[s];
#pragma unroll
        for (int e = 0; e < 8; ++e) acc[e] += a * bf2f(v[e]);
    }
#pragma unroll
    for (int e = 0; e < 8; ++e) atomicAdd(&g_ctx[d0 + e], acc[e]);
}

// ---------------- heads ----------------
__global__ __launch_bounds__(256) void heads_k(const float* __restrict__ Wsym, const float* __restrict__ bsym,
                                               const float* __restrict__ Wrel, const float* __restrict__ brel,
                                               float* __restrict__ out) {
    int wv = threadIdx.x >> 6, lane = threadIdx.x & 63;
    int row = blockIdx.x * 4 + wv;
    if (row >= VV + RR) return;
    const float* wp;
    float bb;
    if (row < VV) { wp = Wsym + (size_t)row * DD; bb = bsym[row]; }
    else          { wp = Wrel + (size_t)(row - VV) * DD; bb = brel[row - VV]; }
    float acc = 0.0f;
#pragma unroll
    for (int j = 0; j < 4; ++j) {
        int base = j * 512 + lane * 8;
        f32x4 w0 = *(const f32x4*)&wp[base];
        f32x4 w1 = *(const f32x4*)&wp[base + 4];
        f32x4 x0 = *(const f32x4*)&g_cb[base];
        f32x4 x1 = *(const f32x4*)&g_cb[base + 4];
#pragma unroll
        for (int e = 0; e < 4; ++e) acc += w0[e] * x0[e] + w1[e] * x1[e];
    }
#pragma unroll
    for (int o = 1; o < 64; o <<= 1) acc += __shfl_xor(acc, o);
    if (lane == 0) out[row] = acc + bb;
}

extern "C" void kernel_launch(void* const* d_in, const int* in_sizes, int n_in,
                              void* d_out, int out_size, void* d_ws, size_t ws_size,
                              hipStream_t stream) {
    float* out = (float*)d_out;   // f32 outputs

    static const int expected[24] = {
        SS * DD, DD, DD, DD,
        3 * DD * DD, 3 * DD * DD, 3 * DD, 3 * DD,
        3 * DD * DD, 3 * DD * DD, 3 * DD, 3 * DD,
        DD * DD, DD, DD * DD, DD, DD * DD, DD,
        DD, 1, VV * DD, VV, RR * DD, RR
    };
    if (n_in != 24) { diag_k<<<1, 1, 0, stream>>>(out, 4.0e7f); return; }
    for (int i = 0; i < 24; ++i)
        if (in_sizes[i] != expected[i]) { diag_k<<<1, 1, 0, stream>>>(out, 3.0e7f + (i + 1) * 1.0e5f); return; }

    const float* enc     = (const float*)d_in[0];
    const float* cprev   = (const float*)d_in[1];
    const float* partner = (const float*)d_in[2];
    const float* cov     = (const float*)d_in[3];
    const float* Wih_a   = (const float*)d_in[4];
    const float* Whh_a   = (const float*)d_in[5];
    const float* bih_a   = (const float*)d_in[6];
    const float* bhh_a   = (const float*)d_in[7];
    const float* Wih_b   = (const float*)d_in[8];
    const float* Whh_b   = (const float*)d_in[9];
    const float* bih_b   = (const float*)d_in[10];
    const float* bhh_b   = (const float*)d_in[11];
    const float* W_enc   = (const float*)d_in[12];
    const float* b_enc   = (const float*)d_in[13];
    const float* W_co    = (const float*)d_in[14];
    const float* b_co    = (const float*)d_in[15];
    const float* W_cov   = (const float*)d_in[16];
    const float* b_cov   = (const float*)d_in[17];
    const float* W_score = (const float*)d_in[18];
    const float* W_sym   = (const float*)d_in[20];
    const float* b_sym   = (const float*)d_in[21];
    const float* W_rel   = (const float*)d_in[22];
    const float* b_rel   = (const float*)d_in[23];

    presplit_all_k<<<SS + DD * DD / (256 * 8), 256, 0, stream>>>(enc, W_enc);
    matvec2_k<0><<<2 * (GATE / 4), 256, 0, stream>>>(Wih_a, Whh_a, partner, cprev, bih_a, bhh_a);
    gru_out_k<0><<<8, 256, 0, stream>>>(cprev, nullptr);
    cc_k<<<DD / 4, 256, 0, stream>>>(W_co, W_cov, cov, b_enc, b_co, b_cov);
    score_gemm_k<<<1024, 256, 0, stream>>>(W_score);
    softmax_k<<<1, 1024, 0, stream>>>(out + VV + RR + DD);
    ctx_partial_k<<<128, 256, 0, stream>>>();
    matvec2_k<1><<<2 * (GATE / 4), 256, 0, stream>>>(Wih_b, Whh_b, nullptr, nullptr, bih_b, bhh_b);
    gru_out_k<1><<<8, 256, 0, stream>>>(cprev, out + VV + RR);
    heads_k<<<(VV + RR + 3) / 4, 256, 0, stream>>>(W_sym, b_sym, W_rel, b_rel, out);
}

// Round 22
// 238.274 us; speedup vs baseline: 1.6176x; 1.1066x over previous
//
#include <hip/hip_runtime.h>
#include <hip/hip_bf16.h>
#include <math.h>

#define DD 2048
#define SS 8192
#define VV 32002
#define RR 7
#define GATE 6144

typedef unsigned short u16;
typedef __attribute__((ext_vector_type(8))) unsigned short u16x8;
typedef __attribute__((ext_vector_type(8))) short bfrag;   // 8 bf16 = 4 VGPRs
typedef __attribute__((ext_vector_type(4))) float f32x4;

// ---- static device scratch: referenced ONLY from device code ----
__device__ __attribute__((aligned(256))) u16 g_ah[(size_t)SS * DD];   // enc as bf16 (32 MB)
__device__ __attribute__((aligned(256))) u16 g_bh[(size_t)DD * DD];   // W_enc as bf16 (8 MB)
__device__ __attribute__((aligned(256))) float g_gia[GATE], g_gha[GATE], g_gib[GATE], g_ghb[GATE];
__device__ __attribute__((aligned(256))) float g_co[DD], g_cc[DD], g_ctx[DD], g_cb[DD];
__device__ __attribute__((aligned(256))) float g_alpha[SS];
__device__ __attribute__((aligned(256))) float g_scores[SS];

__device__ __forceinline__ float fsigmoid(float x) { return 1.0f / (1.0f + __expf(-x)); }
__device__ __forceinline__ float ftanh(float x)    { return 1.0f - 2.0f / (__expf(2.0f * x) + 1.0f); }
__device__ __forceinline__ u16 f2bf(float v) {
    union { float f; unsigned int i; } c; c.f = v;
    return (u16)((c.i + 0x7FFF + ((c.i >> 16) & 1)) >> 16);   // RNE
}
__device__ __forceinline__ float bf2f(u16 u) {
    union { unsigned int i; float f; } c; c.i = ((unsigned int)u) << 16; return c.f;
}
__device__ __forceinline__ void gload16(const void* g, void* l) {
    __builtin_amdgcn_global_load_lds(
        (const __attribute__((address_space(1))) void*)g,
        (__attribute__((address_space(3))) void*)l, 16, 0, 0);
}

__global__ void diag_k(float* out, float v) { out[0] = v; }

// ---------------- fused presplit: blocks [0,8192) -> enc, [8192,10240) -> W_enc; + zero-init ----------------
__global__ __launch_bounds__(256) void presplit_all_k(const float* __restrict__ enc,
                                                      const float* __restrict__ wenc) {
    int b = blockIdx.x;
    const float* src;
    u16* dst;
    size_t i;
    if (b < SS) { src = enc;  dst = g_ah; i = ((size_t)b * 256 + threadIdx.x) * 8; }
    else        { src = wenc; dst = g_bh; i = ((size_t)(b - SS) * 256 + threadIdx.x) * 8; }
    f32x4 v0 = *(const f32x4*)&src[i];
    f32x4 v1 = *(const f32x4*)&src[i + 4];
    u16x8 h;
#pragma unroll
    for (int e = 0; e < 4; ++e) { h[e] = f2bf(v0[e]); h[4 + e] = f2bf(v1[e]); }
    *(u16x8*)&dst[i] = h;
    if (b >= SS) {   // zero accumulators (2048 blocks x 256 threads covers SS)
        int gt = (b - SS) * 256 + threadIdx.x;
        if (gt < SS) g_scores[gt] = 0.0f;
        if (gt < DD) g_ctx[gt] = 0.0f;
    }
}

// ---------------- fused matvec pair: PAIR 0 -> {gi_a, gh_a}, PAIR 1 -> {gi_b, gh_b} ----------------
template<int PAIR>
__global__ __launch_bounds__(256) void matvec2_k(const float* __restrict__ W0,
                                                 const float* __restrict__ W1,
                                                 const float* __restrict__ x0_in,
                                                 const float* __restrict__ x1_in,
                                                 const float* __restrict__ b0,
                                                 const float* __restrict__ b1) {
    const int half = blockIdx.x >= (GATE / 4);
    const float* W    = half ? W1 : W0;
    const float* bias = half ? b1 : b0;
    const float* x;
    float* out;
    if (PAIR == 0) { x = half ? x1_in : x0_in; out = half ? g_gha : g_gia; }
    else           { x = half ? g_co  : g_ctx; out = half ? g_ghb : g_gib; }
    int wv = threadIdx.x >> 6, lane = threadIdx.x & 63;
    int row = (blockIdx.x - half * (GATE / 4)) * 4 + wv;
    const float* wp = W + (size_t)row * DD;
    float acc = 0.0f;
#pragma unroll
    for (int j = 0; j < 4; ++j) {
        int base = j * 512 + lane * 8;
        f32x4 w0 = *(const f32x4*)&wp[base];
        f32x4 w1 = *(const f32x4*)&wp[base + 4];
        f32x4 x0 = *(const f32x4*)&x[base];
        f32x4 x1 = *(const f32x4*)&x[base + 4];
#pragma unroll
        for (int e = 0; e < 4; ++e) acc += w0[e] * x0[e] + w1[e] * x1[e];
    }
#pragma unroll
    for (int o = 1; o < 64; o <<= 1) acc += __shfl_xor(acc, o);
    if (lane == 0) out[row] = acc + bias[row];
}

// ---------------- GRU pointwise ----------------
template<int B>
__global__ void gru_out_k(const float* __restrict__ h_in, float* __restrict__ out_f) {
    const float* gi = B ? g_gib : g_gia;
    const float* gh = B ? g_ghb : g_gha;
    int d = blockIdx.x * 256 + threadIdx.x;
    float hh = B ? g_co[d] : h_in[d];
    float r = fsigmoid(gi[d] + gh[d]);
    float z = fsigmoid(gi[DD + d] + gh[DD + d]);
    float n = ftanh(gi[2 * DD + d] + r * gh[2 * DD + d]);
    float c = (1.0f - z) * n + z * hh;
    if (B) { g_cb[d] = c; out_f[d] = c; }
    else   { g_co[d] = c; }
}

// ---------------- cc[n] = W_co[n].c_o + W_cov[n].cov + b_enc+b_co+b_cov ----------------
__global__ __launch_bounds__(256) void cc_k(const float* __restrict__ Wco, const float* __restrict__ Wcov,
                                            const float* __restrict__ cov,
                                            const float* __restrict__ benc, const float* __restrict__ bco,
                                            const float* __restrict__ bcov) {
    int wv = threadIdx.x >> 6, lane = threadIdx.x & 63;
    int row = blockIdx.x * 4 + wv;
    const float* p1 = Wco + (size_t)row * DD;
    const float* p2 = Wcov + (size_t)row * DD;
    float acc = 0.0f;
#pragma unroll
    for (int j = 0; j < 4; ++j) {
        int base = j * 512 + lane * 8;
        f32x4 u0 = *(const f32x4*)&p1[base];
        f32x4 u1 = *(const f32x4*)&p1[base + 4];
        f32x4 v0 = *(const f32x4*)&p2[base];
        f32x4 v1 = *(const f32x4*)&p2[base + 4];
        f32x4 a0 = *(const f32x4*)&g_co[base];
        f32x4 a1 = *(const f32x4*)&g_co[base + 4];
        f32x4 b0 = *(const f32x4*)&cov[base];
        f32x4 b1 = *(const f32x4*)&cov[base + 4];
#pragma unroll
        for (int e = 0; e < 4; ++e)
            acc += u0[e] * a0[e] + u1[e] * a1[e] + v0[e] * b0[e] + v1[e] * b1[e];
    }
#pragma unroll
    for (int o = 1; o < 64; o <<= 1) acc += __shfl_xor(acc, o);
    if (lane == 0) g_cc[row] = acc + benc[row] + bco[row] + bcov[row];
}

// ---------------- fused e-GEMM + tanh-score epilogue ----------------
// 256x256 tile (halves L2 traffic vs 128^2), BK=32, 8 waves (2x4), 512 threads.
// Counted-vmcnt dbuf (round-21 scheme) + chunk-XOR swizzle for 64B rows:
// phys_chunk = chunk ^ ((row>>1)&3)  -> 2-way LDS banks (free).
// Grid 256 = 1 block/CU; bn = bid&7 -> each XCD owns one 1MB B-panel (L2-resident).
__global__ __launch_bounds__(512) void score_gemm_k(const float* __restrict__ Wsc) {
    __shared__ u16 As[2][256 * 32];
    __shared__ u16 Bs[2][256 * 32];
    const int bid = blockIdx.x;
    const int bn = bid & 7;       // 0..7  (XCD-resident B panel)
    const int bm = bid >> 3;      // 0..31
    const int tid = threadIdx.x;
    const int wave = tid >> 6, lane = tid & 63;
    const int wr = wave >> 2, wc = wave & 3;   // 2 x 4 wave grid; wave out = 128m x 64n
    const int rsel = lane & 15;
    const int lch = lane >> 4;                 // logical chunk 0..3 (k-group)

    f32x4 acc[8][4];
#pragma unroll
    for (int m = 0; m < 8; ++m)
#pragma unroll
        for (int n = 0; n < 4; ++n) acc[m][n] = f32x4{0.f, 0.f, 0.f, 0.f};

    const u16* gA = g_ah + (size_t)(bm * 256) * DD;
    const u16* gB = g_bh + (size_t)(bn * 256) * DD;

    // staging: 1024 chunks (16B) per operand; thread t covers c = t, t+512
    const int c0 = tid, c1 = tid + 512;
    const int r0 = c0 >> 2, ch0 = c0 & 3;
    const int r1 = c1 >> 2, ch1 = c1 & 3;
    const size_t ga0 = (size_t)r0 * DD + ((ch0 ^ ((r0 >> 1) & 3)) * 8);
    const size_t ga1 = (size_t)r1 * DD + ((ch1 ^ ((r1 >> 1) & 3)) * 8);

    // prologue: stage tile 0 into buffer 0 (4 loads in flight)
    gload16(gA + ga0, &As[0][c0 * 8]);
    gload16(gA + ga1, &As[0][c1 * 8]);
    gload16(gB + ga0, &Bs[0][c0 * 8]);
    gload16(gB + ga1, &Bs[0][c1 * 8]);

    int cur = 0;
    for (int step = 0; step < 64; ++step) {
        if (step < 63) {
            size_t k1 = (size_t)(step + 1) * 32;
            gload16(gA + ga0 + k1, &As[cur ^ 1][c0 * 8]);
            gload16(gA + ga1 + k1, &As[cur ^ 1][c1 * 8]);
            gload16(gB + ga0 + k1, &Bs[cur ^ 1][c0 * 8]);
            gload16(gB + ga1 + k1, &Bs[cur ^ 1][c1 * 8]);
            asm volatile("s_waitcnt vmcnt(4)" ::: "memory");   // tile-t loads done; t+1 in flight
        } else {
            asm volatile("s_waitcnt vmcnt(0)" ::: "memory");
        }
        __builtin_amdgcn_s_barrier();
        __builtin_amdgcn_sched_barrier(0);
        // fragment reads: row_local = base + rsel; phys chunk = lch ^ ((rsel>>1)&3)
        const int pch = (lch ^ ((rsel >> 1) & 3)) * 8;
        bfrag a[8], b[4];
#pragma unroll
        for (int m = 0; m < 8; ++m) {
            int row = wr * 128 + m * 16 + rsel;
            a[m] = *(const bfrag*)&As[cur][row * 32 + pch];
        }
#pragma unroll
        for (int n = 0; n < 4; ++n) {
            int row = wc * 64 + n * 16 + rsel;
            b[n] = *(const bfrag*)&Bs[cur][row * 32 + pch];
        }
#pragma unroll
        for (int m = 0; m < 8; ++m)
#pragma unroll
            for (int n = 0; n < 4; ++n)
                acc[m][n] = __builtin_amdgcn_mfma_f32_16x16x32_bf16(a[m], b[n], acc[m][n], 0, 0, 0);
        __builtin_amdgcn_s_barrier();
        __builtin_amdgcn_sched_barrier(0);
        cur ^= 1;
    }

    // epilogue: tanh + weighted reduce over this wave's 64 n-columns -> atomic scores
    const int cl = lane & 15, gq = lane >> 4;
    float ccv[4], wv[4];
#pragma unroll
    for (int nf = 0; nf < 4; ++nf) {
        int n = bn * 256 + wc * 64 + nf * 16 + cl;
        ccv[nf] = g_cc[n];
        wv[nf] = Wsc[n];
    }
#pragma unroll
    for (int m = 0; m < 8; ++m) {
#pragma unroll
        for (int r = 0; r < 4; ++r) {
            float v = 0.0f;
#pragma unroll
            for (int nf = 0; nf < 4; ++nf) v += ftanh(acc[m][nf][r] + ccv[nf]) * wv[nf];
            v += __shfl_xor(v, 1); v += __shfl_xor(v, 2);
            v += __shfl_xor(v, 4); v += __shfl_xor(v, 8);
            if (cl == 0) atomicAdd(&g_scores[bm * 256 + wr * 128 + m * 16 + gq * 4 + r], v);
        }
    }
}

// ---------------- softmax over 8192 scores ----------------
__global__ __launch_bounds__(1024) void softmax_k(float* __restrict__ out_alpha) {
    __shared__ float red[16];
    __shared__ float sval;
    int t = threadIdx.x, lane = t & 63, w = t >> 6;
    float loc[8];
    float m = -1e30f;
#pragma unroll
    for (int i = 0; i < 8; ++i) {
        loc[i] = g_scores[t + i * 1024];
        m = fmaxf(m, loc[i]);
    }
#pragma unroll
    for (int o = 1; o < 64; o <<= 1) m = fmaxf(m, __shfl_xor(m, o));
    if (lane == 0) red[w] = m;
    __syncthreads();
    if (t == 0) { float mm = red[0]; for (int i = 1; i < 16; ++i) mm = fmaxf(mm, red[i]); sval = mm; }
    __syncthreads();
    float mx = sval, s = 0.0f;
#pragma unroll
    for (int i = 0; i < 8; ++i) { loc[i] = __expf(loc[i] - mx); s += loc[i]; }
#pragma unroll
    for (int o = 1; o < 64; o <<= 1) s += __shfl_xor(s, o);
    if (lane == 0) red[w] = s;
    __syncthreads();
    if (t == 0) { float ss = 0; for (int i = 0; i < 16; ++i) ss += red[i]; sval = ss; }
    __syncthreads();
    float inv = 1.0f / sval;
#pragma unroll
    for (int i = 0; i < 8; ++i) {
        float a = loc[i] * inv;
        g_alpha[t + i * 1024] = a;
        out_alpha[t + i * 1024] = a;
    }
}

// ---------------- ctx += alpha @ enc  (bf16 enc from g_ah) ----------------
__global__ __launch_bounds__(256) void ctx_partial_k() {
    int t = threadIdx.x, b = blockIdx.x;   // 128 blocks x 64 s-rows
    int d0 = t * 8;
    float acc[8] = {0, 0, 0, 0, 0, 0, 0, 0};
    int s0 = b * 64;
    for (int s = s0; s < s0 + 64; ++s) {
        u16x8 v = *(const u16x8*)&g_ah[(size_t)s * DD + d0];
        float a = g_alpha[s];
#pragma unroll
        for (int e = 0; e < 8; ++e) acc[e] += a * bf2f(v[e]);
    }
#pragma unroll
    for (int e = 0; e < 8; ++e) atomicAdd(&g_ctx[d0 + e], acc[e]);
}

// ---------------- heads ----------------
__global__ __launch_bounds__(256) void heads_k(const float* __restrict__ Wsym, const float* __restrict__ bsym,
                                               const float* __restrict__ Wrel, const float* __restrict__ brel,
                                               float* __restrict__ out) {
    int wv = threadIdx.x >> 6, lane = threadIdx.x & 63;
    int row = blockIdx.x * 4 + wv;
    if (row >= VV + RR) return;
    const float* wp;
    float bb;
    if (row < VV) { wp = Wsym + (size_t)row * DD; bb = bsym[row]; }
    else          { wp = Wrel + (size_t)(row - VV) * DD; bb = brel[row - VV]; }
    float acc = 0.0f;
#pragma unroll
    for (int j = 0; j < 4; ++j) {
        int base = j * 512 + lane * 8;
        f32x4 w0 = *(const f32x4*)&wp[base];
        f32x4 w1 = *(const f32x4*)&wp[base + 4];
        f32x4 x0 = *(const f32x4*)&g_cb[base];
        f32x4 x1 = *(const f32x4*)&g_cb[base + 4];
#pragma unroll
        for (int e = 0; e < 4; ++e) acc += w0[e] * x0[e] + w1[e] * x1[e];
    }
#pragma unroll
    for (int o = 1; o < 64; o <<= 1) acc += __shfl_xor(acc, o);
    if (lane == 0) out[row] = acc + bb;
}

extern "C" void kernel_launch(void* const* d_in, const int* in_sizes, int n_in,
                              void* d_out, int out_size, void* d_ws, size_t ws_size,
                              hipStream_t stream) {
    float* out = (float*)d_out;   // f32 outputs

    static const int expected[24] = {
        SS * DD, DD, DD, DD,
        3 * DD * DD, 3 * DD * DD, 3 * DD, 3 * DD,
        3 * DD * DD, 3 * DD * DD, 3 * DD, 3 * DD,
        DD * DD, DD, DD * DD, DD, DD * DD, DD,
        DD, 1, VV * DD, VV, RR * DD, RR
    };
    if (n_in != 24) { diag_k<<<1, 1, 0, stream>>>(out, 4.0e7f); return; }
    for (int i = 0; i < 24; ++i)
        if (in_sizes[i] != expected[i]) { diag_k<<<1, 1, 0, stream>>>(out, 3.0e7f + (i + 1) * 1.0e5f); return; }

    const float* enc     = (const float*)d_in[0];
    const float* cprev   = (const float*)d_in[1];
    const float* partner = (const float*)d_in[2];
    const float* cov     = (const float*)d_in[3];
    const float* Wih_a   = (const float*)d_in[4];
    const float* Whh_a   = (const float*)d_in[5];
    const float* bih_a   = (const float*)d_in[6];
    const float* bhh_a   = (const float*)d_in[7];
    const float* Wih_b   = (const float*)d_in[8];
    const float* Whh_b   = (const float*)d_in[9];
    const float* bih_b   = (const float*)d_in[10];
    const float* bhh_b   = (const float*)d_in[11];
    const float* W_enc   = (const float*)d_in[12];
    const float* b_enc   = (const float*)d_in[13];
    const float* W_co    = (const float*)d_in[14];
    const float* b_co    = (const float*)d_in[15];
    const float* W_cov   = (const float*)d_in[16];
    const float* b_cov   = (const float*)d_in[17];
    const float* W_score = (const float*)d_in[18];
    const float* W_sym   = (const float*)d_in[20];
    const float* b_sym   = (const float*)d_in[21];
    const float* W_rel   = (const float*)d_in[22];
    const float* b_rel   = (const float*)d_in[23];

    presplit_all_k<<<SS + DD * DD / (256 * 8), 256, 0, stream>>>(enc, W_enc);
    matvec2_k<0><<<2 * (GATE / 4), 256, 0, stream>>>(Wih_a, Whh_a, partner, cprev, bih_a, bhh_a);
    gru_out_k<0><<<8, 256, 0, stream>>>(cprev, nullptr);
    cc_k<<<DD / 4, 256, 0, stream>>>(W_co, W_cov, cov, b_enc, b_co, b_cov);
    score_gemm_k<<<256, 512, 0, stream>>>(W_score);
    softmax_k<<<1, 1024, 0, stream>>>(out + VV + RR + DD);
    ctx_partial_k<<<128, 256, 0, stream>>>();
    matvec2_k<1><<<2 * (GATE / 4), 256, 0, stream>>>(Wih_b, Whh_b, nullptr, nullptr, bih_b, bhh_b);
    gru_out_k<1><<<8, 256, 0, stream>>>(cprev, out + VV + RR);
    heads_k<<<(VV + RR + 3) / 4, 256, 0, stream>>>(W_sym, b_sym, W_rel, b_rel, out);
}